// Round 5
// baseline (201.991 us; speedup 1.0000x reference)
//
#include <hip/hip_runtime.h>
#include <hip/hip_bf16.h>
#include <math.h>

#define LENGTH 4096
#define BATCH  4096
#define CHUNK  16      // timesteps per thread
#define NTHR   256     // threads per block; NTHR*CHUNK == LENGTH (one block per row)
#define NWAVE  (NTHR / 64)

typedef float vf4 __attribute__((ext_vector_type(4)));

// max-plus 2x2 compose: D = A (x) B, D[k][l] = max_m A[k][m] + B[m][l]
__device__ __forceinline__ void mp_compose(
    float a00, float a01, float a10, float a11,
    float b00, float b01, float b10, float b11,
    float& d00, float& d01, float& d10, float& d11) {
  d00 = fmaxf(a00 + b00, a01 + b10);
  d01 = fmaxf(a00 + b01, a01 + b11);
  d10 = fmaxf(a10 + b00, a11 + b10);
  d11 = fmaxf(a10 + b01, a11 + b11);
}

// F <- (S (x) D_u) (x) F     (one timestep applied on the left)
__device__ __forceinline__ void mp_step(
    float& f00, float& f01, float& f10, float& f11, float ui, float q) {
  float a0l0 = f00 - ui, a1l0 = f10 + ui;  // a_m[l] = phi_m + F[m][l]
  float a0l1 = f01 - ui, a1l1 = f11 + ui;
  float n00 = fmaxf(a0l0 + q, a1l0 - q);
  float n10 = fmaxf(a0l0 - q, a1l0 + q);
  float n01 = fmaxf(a0l1 + q, a1l1 - q);
  float n11 = fmaxf(a0l1 - q, a1l1 + q);
  f00 = n00; f01 = n01; f10 = n10; f11 = n11;
}

__global__ __launch_bounds__(NTHR, 4) void chain_bp_kernel(
    const float* __restrict__ jp, const float* __restrict__ bp,
    const int* __restrict__ obs, float* __restrict__ out) {
  const int row  = blockIdx.x;
  const int tid  = threadIdx.x;
  const int lane = tid & 63;
  const int wv   = tid >> 6;

  const float j  = jp[0];
  const float q  = 0.25f * j;              // log psi diag; off-diag = -q
  const float u0 = 0.5f * bp[0];           // log phi[o=0][s=1] ; s=0 is -u
  const float u1 = 0.5f * bp[1];
  const float wb = -fabsf(q);              // w_base: 0vec == S (x) (wb,wb)

  // ---- LDS: 8-step chunk-matrix LUT (SoA, conflict-light) + stitch ----
  __shared__ float l00[256], l01[256], l10[256], l11[256];
  __shared__ float lut4[16][4];
  __shared__ float smp[NWAVE][4];  // per-wave full prefix matrix
  __shared__ float sms[NWAVE][4];  // per-wave full suffix matrix

  // ---- load this thread's 16 observations (coalesced int4) ----
  const int t0i = tid * CHUNK;
  const int4* op = reinterpret_cast<const int4*>(obs + (size_t)row * LENGTH + t0i);
  int4 o0 = op[0], o1 = op[1], o2 = op[2], o3 = op[3];
  float u[CHUNK];
  u[0]=o0.x?u1:u0; u[1]=o0.y?u1:u0; u[2]=o0.z?u1:u0; u[3]=o0.w?u1:u0;
  u[4]=o1.x?u1:u0; u[5]=o1.y?u1:u0; u[6]=o1.z?u1:u0; u[7]=o1.w?u1:u0;
  u[8]=o2.x?u1:u0; u[9]=o2.y?u1:u0; u[10]=o2.z?u1:u0; u[11]=o2.w?u1:u0;
  u[12]=o3.x?u1:u0; u[13]=o3.y?u1:u0; u[14]=o3.z?u1:u0; u[15]=o3.w?u1:u0;
  // bit k of index = obs at in-chunk step (base+k); step 0 is rightmost factor
  int idxlo = o0.x | (o0.y<<1) | (o0.z<<2) | (o0.w<<3)
            | (o1.x<<4) | (o1.y<<5) | (o1.z<<6) | (o1.w<<7);
  int idxhi = o2.x | (o2.y<<1) | (o2.z<<2) | (o2.w<<3)
            | (o3.x<<4) | (o3.y<<5) | (o3.z<<6) | (o3.w<<7);

  // ---- build 4-bit LUT (16 threads), then 8-bit LUT (all 256 threads) ----
  if (tid < 16) {
    float ua = (tid & 1) ? u1 : u0;
    float f00 = -ua + q, f01 = ua - q, f10 = -ua - q, f11 = ua + q;
#pragma unroll
    for (int k = 1; k < 4; ++k)
      mp_step(f00, f01, f10, f11, ((tid >> k) & 1) ? u1 : u0, q);
    lut4[tid][0] = f00; lut4[tid][1] = f01; lut4[tid][2] = f10; lut4[tid][3] = f11;
  }
  __syncthreads();
  {
    int hi = tid >> 4, lo = tid & 15;
    float a00 = lut4[hi][0], a01 = lut4[hi][1], a10 = lut4[hi][2], a11 = lut4[hi][3];
    float c00 = lut4[lo][0], c01 = lut4[lo][1], c10 = lut4[lo][2], c11 = lut4[lo][3];
    float d00, d01, d10, d11;
    mp_compose(a00, a01, a10, a11, c00, c01, c10, c11, d00, d01, d10, d11);
    l00[tid] = d00; l01[tid] = d01; l10[tid] = d10; l11[tid] = d11;
  }
  __syncthreads();

  // ---- chunk forward matrix F = LUT[hi8] (x) LUT[lo8] ----
  float f00, f01, f10, f11;
  {
    float a00 = l00[idxhi], a01 = l01[idxhi], a10 = l10[idxhi], a11 = l11[idxhi];
    float c00 = l00[idxlo], c01 = l01[idxlo], c10 = l10[idxlo], c11 = l11[idxlo];
    mp_compose(a00, a01, a10, a11, c00, c01, c10, c11, f00, f01, f10, f11);
  }

  // ---- interleaved wave scans: prefix X over F, suffix Y over F^T ----
  float x00 = f00, x01 = f01, x10 = f10, x11 = f11;
  float y00 = f00, y01 = f10, y10 = f01, y11 = f11;  // transpose
#pragma unroll
  for (int d = 1; d < 64; d <<= 1) {
    float px00 = __shfl_up(x00, d), px01 = __shfl_up(x01, d);
    float px10 = __shfl_up(x10, d), px11 = __shfl_up(x11, d);
    float py00 = __shfl_down(y00, d), py01 = __shfl_down(y01, d);
    float py10 = __shfl_down(y10, d), py11 = __shfl_down(y11, d);
    if (lane >= d) {
      float n00, n01, n10, n11;
      mp_compose(x00, x01, x10, x11, px00, px01, px10, px11, n00, n01, n10, n11);
      x00 = n00; x01 = n01; x10 = n10; x11 = n11;
    }
    if (lane + d < 64) {
      float n00, n01, n10, n11;
      mp_compose(y00, y01, y10, y11, py00, py01, py10, py11, n00, n01, n10, n11);
      y00 = n00; y01 = n01; y10 = n10; y11 = n11;
    }
  }

  // ---- cross-wave stitch ----
  if (lane == 63) { smp[wv][0] = x00; smp[wv][1] = x01; smp[wv][2] = x10; smp[wv][3] = x11; }
  if (lane == 0)  { sms[wv][0] = y00; sms[wv][1] = y01; sms[wv][2] = y10; sms[wv][3] = y11; }
  __syncthreads();

  // fhead = W_{wv-1} (x) ... (x) W_0 (x) 0vec
  float fh0 = 0.f, fh1 = 0.f;
  for (int k = 0; k < wv; ++k) {
    float m00 = smp[k][0], m01 = smp[k][1], m10 = smp[k][2], m11 = smp[k][3];
    float n0 = fmaxf(m00 + fh0, m01 + fh1);
    float n1 = fmaxf(m10 + fh0, m11 + fh1);
    fh0 = n0; fh1 = n1;
  }
  // wtail = V_{wv+1} (x) ... (x) V_{NWAVE-1} (x) w_base
  float wt0 = wb, wt1 = wb;
  for (int k = NWAVE - 1; k > wv; --k) {
    float m00 = sms[k][0], m01 = sms[k][1], m10 = sms[k][2], m11 = sms[k][3];
    float n0 = fmaxf(m00 + wt0, m01 + wt1);
    float n1 = fmaxf(m10 + wt0, m11 + wt1);
    wt0 = n0; wt1 = n1;
  }

  // z_c = X_c (x) fhead = global fwd at start of NEXT chunk; f_in = z_{c-1}
  float z0 = fmaxf(x00 + fh0, x01 + fh1);
  float z1 = fmaxf(x10 + fh0, x11 + fh1);
  float zp0 = __shfl_up(z0, 1), zp1 = __shfl_up(z1, 1);
  float fi0 = (lane == 0) ? fh0 : zp0;
  float fi1 = (lane == 0) ? fh1 : zp1;

  // y_c = Y_c (x) wtail = w_{c-1}; w_c = y_{c+1} (lane 63 -> wtail)
  float yv0 = fmaxf(y00 + wt0, y01 + wt1);
  float yv1 = fmaxf(y10 + wt0, y11 + wt1);
  float yn0 = __shfl_down(yv0, 1), yn1 = __shfl_down(yv1, 1);
  float wc0 = (lane == 63) ? wt0 : yn0;
  float wc1 = (lane == 63) ? wt1 : yn1;
  // g_c = bwd at last t of this chunk = S (x) w_c
  float g0 = fmaxf(q + wc0, -q + wc1);
  float g1 = fmaxf(-q + wc0, q + wc1);

  // ---- backward sweep, partial beliefs (phi + bwd) folded into out regs ----
  float e0v[CHUNK], e1v[CHUNK];
  {
    float r0 = g0, r1 = g1;
    e0v[CHUNK - 1] = r0 - u[CHUNK - 1];
    e1v[CHUNK - 1] = r1 + u[CHUNK - 1];
#pragma unroll
    for (int i = CHUNK - 1; i > 0; --i) {
      float a0 = r0 - u[i], a1 = r1 + u[i];
      r0 = fmaxf(a0 + q, a1 - q);
      r1 = fmaxf(a0 - q, a1 + q);
      e0v[i - 1] = r0 - u[i - 1];
      e1v[i - 1] = r1 + u[i - 1];
    }
  }

  // ---- forward sweep: add fwd, exp in place ----
  float fw0 = fi0, fw1 = fi1;
#pragma unroll
  for (int i = 0; i < CHUNK; ++i) {
    float ui = u[i];
    e0v[i] = __expf(e0v[i] + fw0);
    e1v[i] = __expf(e1v[i] + fw1);
    float a0 = fw0 - ui, a1 = fw1 + ui;
    fw0 = fmaxf(a0 + q, a1 - q);
    fw1 = fmaxf(a0 - q, a1 + q);
  }

  // ---- stores: 8 adjacent float4 ----
  float* outp = out + (size_t)row * (2 * LENGTH) + t0i;
#pragma unroll
  for (int v = 0; v < 4; ++v) {
    vf4 s0 = {e0v[4 * v], e0v[4 * v + 1], e0v[4 * v + 2], e0v[4 * v + 3]};
    *reinterpret_cast<vf4*>(outp + 4 * v) = s0;
  }
#pragma unroll
  for (int v = 0; v < 4; ++v) {
    vf4 s1 = {e1v[4 * v], e1v[4 * v + 1], e1v[4 * v + 2], e1v[4 * v + 3]};
    *reinterpret_cast<vf4*>(outp + LENGTH + 4 * v) = s1;
  }
}

extern "C" void kernel_launch(void* const* d_in, const int* in_sizes, int n_in,
                              void* d_out, int out_size, void* d_ws, size_t ws_size,
                              hipStream_t stream) {
  const float* jp  = (const float*)d_in[0];   // scalar j
  const float* bp  = (const float*)d_in[1];   // b[2]
  const int*   obs = (const int*)d_in[2];     // [BATCH, LENGTH] int32
  float* out = (float*)d_out;                 // [BATCH, 2, LENGTH] fp32

  chain_bp_kernel<<<BATCH, NTHR, 0, stream>>>(jp, bp, obs, out);
}

// Round 6
// 189.079 us; speedup vs baseline: 1.0683x; 1.0683x over previous
//
#include <hip/hip_runtime.h>
#include <math.h>

#define LENGTH 4096
#define BATCH  4096
#define CHUNK  8       // timesteps per thread
#define NTHR   512     // threads per block; NTHR*CHUNK == LENGTH (one block per row)
#define NWAVE  (NTHR / 64)

typedef float vf4 __attribute__((ext_vector_type(4)));

// max-plus 2x2 compose: D = A (x) B, D[k][l] = max_m A[k][m] + B[m][l]
__device__ __forceinline__ void mp_compose(
    float a00, float a01, float a10, float a11,
    float b00, float b01, float b10, float b11,
    float& d00, float& d01, float& d10, float& d11) {
  d00 = fmaxf(a00 + b00, a01 + b10);
  d01 = fmaxf(a00 + b01, a01 + b11);
  d10 = fmaxf(a10 + b00, a11 + b10);
  d11 = fmaxf(a10 + b01, a11 + b11);
}

// F <- (S (x) D_u) (x) F     (one timestep applied on the left)
__device__ __forceinline__ void mp_step(
    float& f00, float& f01, float& f10, float& f11, float ui, float q) {
  float a0l0 = f00 - ui, a1l0 = f10 + ui;  // a_m[l] = phi_m + F[m][l]
  float a0l1 = f01 - ui, a1l1 = f11 + ui;
  float n00 = fmaxf(a0l0 + q, a1l0 - q);
  float n10 = fmaxf(a0l0 - q, a1l0 + q);
  float n01 = fmaxf(a0l1 + q, a1l1 - q);
  float n11 = fmaxf(a0l1 - q, a1l1 + q);
  f00 = n00; f01 = n01; f10 = n10; f11 = n11;
}

__global__ __launch_bounds__(NTHR, 8) void chain_bp_kernel(
    const float* __restrict__ jp, const float* __restrict__ bp,
    const int* __restrict__ obs, float* __restrict__ out) {
  const int row  = blockIdx.x;
  const int tid  = threadIdx.x;
  const int lane = tid & 63;
  const int wv   = tid >> 6;

  // All potentials pre-scaled by log2(e): outputs use raw v_exp_f32 (2^x).
  const float LOG2E = 1.44269504088896f;
  const float j  = jp[0];
  const float q  = 0.25f * j * LOG2E;      // log2 psi diag; off-diag = -q
  const float u0 = 0.5f * bp[0] * LOG2E;   // log2 phi[o=0][s=1] ; s=0 is -u
  const float u1 = 0.5f * bp[1] * LOG2E;
  const float wb = -fabsf(q);              // w_base: 0vec == S (x) (wb,wb)

  // ---- LDS: chunk-matrix LUTs + stitch scratch ----
  __shared__ vf4 lut4s[16];
  __shared__ vf4 lut8[256];
  __shared__ float smp[NWAVE][4];  // per-wave full prefix matrix
  __shared__ float sms[NWAVE][4];  // per-wave full suffix matrix

  // ---- load this thread's 8 observations (two int4) -> u[i], 8-bit idx ----
  const int t0 = tid * CHUNK;
  const int4* op = reinterpret_cast<const int4*>(obs + (size_t)row * LENGTH + t0);
  int4 o0 = op[0], o1 = op[1];
  float u[CHUNK];
  u[0]=o0.x?u1:u0; u[1]=o0.y?u1:u0; u[2]=o0.z?u1:u0; u[3]=o0.w?u1:u0;
  u[4]=o1.x?u1:u0; u[5]=o1.y?u1:u0; u[6]=o1.z?u1:u0; u[7]=o1.w?u1:u0;
  // bit k = obs at in-chunk step k; step 0 is rightmost factor
  int idx = o0.x | (o0.y<<1) | (o0.z<<2) | (o0.w<<3)
          | (o1.x<<4) | (o1.y<<5) | (o1.z<<6) | (o1.w<<7);

  // ---- build 4-bit LUT (16 threads), then 8-bit LUT (256 threads) ----
  if (tid < 16) {
    float ua = (tid & 1) ? u1 : u0;
    float f00 = -ua + q, f01 = ua - q, f10 = -ua - q, f11 = ua + q;
#pragma unroll
    for (int k = 1; k < 4; ++k)
      mp_step(f00, f01, f10, f11, ((tid >> k) & 1) ? u1 : u0, q);
    lut4s[tid] = (vf4){f00, f01, f10, f11};
  }
  __syncthreads();
  if (tid < 256) {
    vf4 a = lut4s[tid >> 4], c = lut4s[tid & 15];
    float d00, d01, d10, d11;
    mp_compose(a[0], a[1], a[2], a[3], c[0], c[1], c[2], c[3], d00, d01, d10, d11);
    lut8[tid] = (vf4){d00, d01, d10, d11};
  }
  __syncthreads();

  // ---- chunk forward matrix F = lut8[idx] (single ds_read_b128 gather) ----
  vf4 Fm = lut8[idx];
  float f00 = Fm[0], f01 = Fm[1], f10 = Fm[2], f11 = Fm[3];

  // ---- interleaved wave scans: prefix X over F, suffix Y over F^T ----
  float x00 = f00, x01 = f01, x10 = f10, x11 = f11;
  float y00 = f00, y01 = f10, y10 = f01, y11 = f11;  // transpose
#pragma unroll
  for (int d = 1; d < 64; d <<= 1) {
    float px00 = __shfl_up(x00, d), px01 = __shfl_up(x01, d);
    float px10 = __shfl_up(x10, d), px11 = __shfl_up(x11, d);
    float py00 = __shfl_down(y00, d), py01 = __shfl_down(y01, d);
    float py10 = __shfl_down(y10, d), py11 = __shfl_down(y11, d);
    if (lane >= d) {
      float n00, n01, n10, n11;
      mp_compose(x00, x01, x10, x11, px00, px01, px10, px11, n00, n01, n10, n11);
      x00 = n00; x01 = n01; x10 = n10; x11 = n11;
    }
    if (lane + d < 64) {
      float n00, n01, n10, n11;
      mp_compose(y00, y01, y10, y11, py00, py01, py10, py11, n00, n01, n10, n11);
      y00 = n00; y01 = n01; y10 = n10; y11 = n11;
    }
  }

  // ---- cross-wave stitch ----
  if (lane == 63) { smp[wv][0] = x00; smp[wv][1] = x01; smp[wv][2] = x10; smp[wv][3] = x11; }
  if (lane == 0)  { sms[wv][0] = y00; sms[wv][1] = y01; sms[wv][2] = y10; sms[wv][3] = y11; }
  __syncthreads();

  // fhead = W_{wv-1} (x) ... (x) W_0 (x) 0vec
  float fh0 = 0.f, fh1 = 0.f;
  for (int k = 0; k < wv; ++k) {
    float m00 = smp[k][0], m01 = smp[k][1], m10 = smp[k][2], m11 = smp[k][3];
    float n0 = fmaxf(m00 + fh0, m01 + fh1);
    float n1 = fmaxf(m10 + fh0, m11 + fh1);
    fh0 = n0; fh1 = n1;
  }
  // wtail = V_{wv+1} (x) ... (x) V_{NWAVE-1} (x) w_base
  float wt0 = wb, wt1 = wb;
  for (int k = NWAVE - 1; k > wv; --k) {
    float m00 = sms[k][0], m01 = sms[k][1], m10 = sms[k][2], m11 = sms[k][3];
    float n0 = fmaxf(m00 + wt0, m01 + wt1);
    float n1 = fmaxf(m10 + wt0, m11 + wt1);
    wt0 = n0; wt1 = n1;
  }

  // z_c = X_c (x) fhead = global fwd at start of NEXT chunk; f_in = z_{c-1}
  float z0 = fmaxf(x00 + fh0, x01 + fh1);
  float z1 = fmaxf(x10 + fh0, x11 + fh1);
  float zp0 = __shfl_up(z0, 1), zp1 = __shfl_up(z1, 1);
  float fi0 = (lane == 0) ? fh0 : zp0;
  float fi1 = (lane == 0) ? fh1 : zp1;

  // y_c = Y_c (x) wtail = w_{c-1}; w_c = y_{c+1} (lane 63 -> wtail)
  float yv0 = fmaxf(y00 + wt0, y01 + wt1);
  float yv1 = fmaxf(y10 + wt0, y11 + wt1);
  float yn0 = __shfl_down(yv0, 1), yn1 = __shfl_down(yv1, 1);
  float wc0 = (lane == 63) ? wt0 : yn0;
  float wc1 = (lane == 63) ? wt1 : yn1;
  // g_c = bwd at last t of this chunk = S (x) w_c
  float g0 = fmaxf(q + wc0, -q + wc1);
  float g1 = fmaxf(-q + wc0, q + wc1);

  // ---- in-chunk backward sweep (registers): b[i] = bwd[t0+i] ----
  float b0[CHUNK], b1[CHUNK];
  b0[CHUNK - 1] = g0; b1[CHUNK - 1] = g1;
#pragma unroll
  for (int i = CHUNK - 1; i > 0; --i) {
    float ui = u[i];
    float a0 = b0[i] - ui;
    float a1 = b1[i] + ui;
    b0[i - 1] = fmaxf(a0 + q, a1 - q);
    b1[i - 1] = fmaxf(a0 - q, a1 + q);
  }

  // ---- in-chunk forward sweep + belief (exp2); buffer, 4 adjacent stores ----
  float fw0 = fi0, fw1 = fi1;
  vf4 p0lo, p0hi, p1lo, p1hi;  // plane0/plane1, elements 0..3 / 4..7
#pragma unroll
  for (int i = 0; i < CHUNK; ++i) {
    float ui = u[i];
    float e0 = __builtin_amdgcn_exp2f(-ui + fw0 + b0[i]);
    float e1 = __builtin_amdgcn_exp2f( ui + fw1 + b1[i]);
    if (i < 4) { p0lo[i] = e0; p1lo[i] = e1; }
    else       { p0hi[i - 4] = e0; p1hi[i - 4] = e1; }
    float a0 = fw0 - ui, a1 = fw1 + ui;
    fw0 = fmaxf(a0 + q, a1 - q);
    fw1 = fmaxf(a0 - q, a1 + q);
  }
  float* outp = out + (size_t)row * (2 * LENGTH) + t0;
  *reinterpret_cast<vf4*>(outp)              = p0lo;
  *reinterpret_cast<vf4*>(outp + 4)          = p0hi;
  *reinterpret_cast<vf4*>(outp + LENGTH)     = p1lo;
  *reinterpret_cast<vf4*>(outp + LENGTH + 4) = p1hi;
}

extern "C" void kernel_launch(void* const* d_in, const int* in_sizes, int n_in,
                              void* d_out, int out_size, void* d_ws, size_t ws_size,
                              hipStream_t stream) {
  const float* jp  = (const float*)d_in[0];   // scalar j
  const float* bp  = (const float*)d_in[1];   // b[2]
  const int*   obs = (const int*)d_in[2];     // [BATCH, LENGTH] int32
  float* out = (float*)d_out;                 // [BATCH, 2, LENGTH] fp32

  chain_bp_kernel<<<BATCH, NTHR, 0, stream>>>(jp, bp, obs, out);
}